// Round 16
// baseline (223.614 us; speedup 1.0000x reference)
//
#include <hip/hip_runtime.h>

#define BB 8
#define NN 8700
#define CC 256
#define QQ 300
#define HH 8
#define DD 32
#define HIDN 1024
#define NSPLIT 16
#define TSTR (NSPLIT * 64)
#define KSLACK 1536
#define PADN (NN + KSLACK)

typedef unsigned short u16;
typedef __attribute__((ext_vector_type(8))) short short8;
typedef __attribute__((ext_vector_type(4))) float f32x4;

#define MFMA16(a, b, c) __builtin_amdgcn_mfma_f32_16x16x32_bf16((a), (b), (c), 0, 0, 0)

__device__ __forceinline__ unsigned int cvtpk(float lo, float hi) {
    unsigned int r;
    asm("v_cvt_pk_bf16_f32 %0, %1, %2" : "=v"(r) : "v"(lo), "v"(hi));
    return r;
}
__device__ __forceinline__ u16 f2b_hw(float f) { return (u16)cvtpk(f, 0.f); }
__device__ __forceinline__ float b2f(u16 u) {
    unsigned int x = ((unsigned int)u) << 16;
    return __builtin_bit_cast(float, x);
}
__device__ __forceinline__ void gload16(const u16* g, u16* l) {
    __builtin_amdgcn_global_load_lds(
        (const __attribute__((address_space(1))) void*)g,
        (__attribute__((address_space(3))) void*)l, 16, 0, 0);
}

// ---------------- fused: LN1 (+context out) ∪ weight transpose ----------------
__global__ __launch_bounds__(256)
void prep_k(const float* __restrict__ x, const float* __restrict__ ln1w,
            const float* __restrict__ ln1b, const float* __restrict__ g1,
            u16* __restrict__ xn, float* __restrict__ out,
            const float* __restrict__ Wq, const float* __restrict__ Wk,
            const float* __restrict__ Wv, const float* __restrict__ Wp,
            const float* __restrict__ W1, const float* __restrict__ W2,
            u16* __restrict__ wdst, float qscale)
{
    __shared__ u16 tl[64][66];
    if (blockIdx.x < 17400) {
        int row = blockIdx.x * 4 + (threadIdx.x >> 6);
        int l = threadIdx.x & 63;
        size_t base = (size_t)row * CC + l * 4;
        float4 xv = *reinterpret_cast<const float4*>(x + base);
        float s  = xv.x + xv.y + xv.z + xv.w;
        float s2 = xv.x * xv.x + xv.y * xv.y + xv.z * xv.z + xv.w * xv.w;
#pragma unroll
        for (int m = 1; m < 64; m <<= 1) {
            s  += __shfl_xor(s,  m, 64);
            s2 += __shfl_xor(s2, m, 64);
        }
        float mean = s * (1.0f / CC);
        float rs = rsqrtf(s2 * (1.0f / CC) - mean * mean + 1e-5f);
        float4 wv = *reinterpret_cast<const float4*>(ln1w + l * 4);
        float4 bb = *reinterpret_cast<const float4*>(ln1b + l * 4);
        float n0 = (xv.x - mean) * rs * wv.x + bb.x;
        float n1 = (xv.y - mean) * rs * wv.y + bb.y;
        float n2 = (xv.z - mean) * rs * wv.z + bb.z;
        float n3 = (xv.w - mean) * rs * wv.w + bb.w;
        uint2 u; u.x = cvtpk(n0, n1); u.y = cvtpk(n2, n3);
        *reinterpret_cast<uint2*>(xn + base) = u;
        int n = row % NN;
        if (n >= QQ) {
            float4 gv = *reinterpret_cast<const float4*>(g1 + l * 4);
            float4 o;
            o.x = 2.0f * (xv.x + gv.x * n0);
            o.y = 2.0f * (xv.y + gv.y * n1);
            o.z = 2.0f * (xv.z + gv.z * n2);
            o.w = 2.0f * (xv.w + gv.w * n3);
            *reinterpret_cast<float4*>(out + base) = o;
        }
    } else {
        int bid = blockIdx.x - 17400;
        const float* src; int K, N, tr, tc; size_t dof; float sc = 1.f;
        if (bid < 64) {
            int mat = bid >> 4, ti = bid & 15;
            src = (mat == 0) ? Wq : (mat == 1) ? Wk : (mat == 2) ? Wv : Wp;
            K = 256; N = 256; tr = ti >> 2; tc = ti & 3;
            dof = (size_t)mat * 65536;
            if (mat == 0) sc = qscale;
        } else if (bid < 128) {
            int ti = bid - 64; src = W1; K = 256; N = 1024; tr = ti >> 4; tc = ti & 15; dof = 262144;
        } else {
            int ti = bid - 128; src = W2; K = 1024; N = 256; tr = ti >> 2; tc = ti & 3; dof = 524288;
        }
        int tid = threadIdx.x;
        int jj = tid & 63;
        int i0 = tid >> 6;
#pragma unroll
        for (int ii = 0; ii < 16; ii++) {
            int kk = i0 * 16 + ii;
            float v = src[(size_t)(tr * 64 + kk) * N + tc * 64 + jj] * sc;
            tl[kk][jj] = f2b_hw(v);
        }
        __syncthreads();
#pragma unroll
        for (int ii = 0; ii < 16; ii++) {
            int nn = i0 * 16 + ii;
            wdst[dof + (size_t)(tc * 64 + nn) * K + tr * 64 + jj] = tl[jj][nn];
        }
    }
}

// ---------------- KV (+Q) projection: head-major outputs, A staged once ----------------
__global__ __launch_bounds__(512)
void gemm_kv(const u16* __restrict__ A, const u16* __restrict__ WT,
             const u16* __restrict__ WqT,
             u16* __restrict__ Cb, u16* __restrict__ Cb2, u16* __restrict__ Cq, int M)
{
    __shared__ u16 alds[64 * 256];   // 32 KiB
    const int tid = threadIdx.x;
    const int w = tid >> 6, l = tid & 63;
    const int l15 = l & 15, kg = l >> 4;
    const int rowbase = blockIdx.x * 64;
    const f32x4 fz = {0.f, 0.f, 0.f, 0.f};

    {
        const char* gb = (const char*)(A + (size_t)rowbase * CC);
        char* lb = (char*)alds;
#pragma unroll
        for (int j = 0; j < 4; j++) {
            int o = tid * 64 + j * 16;
            short8 v = *reinterpret_cast<const short8*>(gb + o);
            int d = o ^ (((o >> 9) & 7) << 4);
            *reinterpret_cast<short8*>(lb + d) = v;
        }
    }
    __syncthreads();

    const int colbase = w * 64;
    const u16* bp[4];
#pragma unroll
    for (int ni = 0; ni < 4; ni++)
        bp[ni] = WT + (size_t)(colbase + ni * 16 + l15) * CC + kg * 8;

    f32x4 acc[4][4];
#pragma unroll
    for (int mi = 0; mi < 4; mi++)
#pragma unroll
        for (int ni = 0; ni < 4; ni++) acc[mi][ni] = fz;

    const char* lb = (const char*)alds;
    const int sw = (l15 & 7) << 4;
    int abase[4];
#pragma unroll
    for (int mi = 0; mi < 4; mi++) abase[mi] = (mi * 16 + l15) << 9;

#pragma unroll
    for (int ks = 0; ks < 8; ks++) {
        const int koff = ((ks * 64) + (kg * 16)) ^ sw;
        short8 a[4], bfr[4];
#pragma unroll
        for (int mi = 0; mi < 4; mi++)
            a[mi] = *reinterpret_cast<const short8*>(lb + abase[mi] + koff);
#pragma unroll
        for (int ni = 0; ni < 4; ni++)
            bfr[ni] = *reinterpret_cast<const short8*>(bp[ni] + ks * 32);
#pragma unroll
        for (int mi = 0; mi < 4; mi++)
#pragma unroll
            for (int ni = 0; ni < 4; ni++)
                acc[mi][ni] = MFMA16(bfr[ni], a[mi], acc[mi][ni]);
    }

#pragma unroll
    for (int mi = 0; mi < 4; mi++) {
        int r = rowbase + mi * 16 + l15;
        if (r >= M) continue;
        int bb = r / NN, n = r - bb * NN;
#pragma unroll
        for (int ni = 0; ni < 4; ni++) {
            int col0 = colbase + ni * 16 + kg * 4;
            f32x4 v = acc[mi][ni];
            uint2 pk; pk.x = cvtpk(v[0], v[1]); pk.y = cvtpk(v[2], v[3]);
            int c = (col0 < CC) ? col0 : col0 - CC;
            int hb = (c >> 5) * BB + bb;
            size_t off = ((size_t)hb * PADN + n) * DD + (c & 31);
            if (col0 < CC) *reinterpret_cast<uint2*>(Cb  + off) = pk;
            else           *reinterpret_cast<uint2*>(Cb2 + off) = pk;
        }
    }

    // ---- fused Q projection: only blocks whose row window touches a batch's first QQ rows ----
    {
        int n0 = rowbase % NN;
        bool hasq = (n0 < QQ) || (n0 + 64 > NN);
        if (!hasq) return;

        const u16* qp[4];
#pragma unroll
        for (int ni = 0; ni < 4; ni++)
            qp[ni] = WqT + (size_t)(colbase + ni * 16 + l15) * CC + kg * 8;

        f32x4 qa[4][4];
#pragma unroll
        for (int mi = 0; mi < 4; mi++)
#pragma unroll
            for (int ni = 0; ni < 4; ni++) qa[mi][ni] = fz;

#pragma unroll
        for (int ks = 0; ks < 8; ks++) {
            const int koff = ((ks * 64) + (kg * 16)) ^ sw;
            short8 a[4], bfr[4];
#pragma unroll
            for (int mi = 0; mi < 4; mi++)
                a[mi] = *reinterpret_cast<const short8*>(lb + abase[mi] + koff);
#pragma unroll
            for (int ni = 0; ni < 4; ni++)
                bfr[ni] = *reinterpret_cast<const short8*>(qp[ni] + ks * 32);
#pragma unroll
            for (int mi = 0; mi < 4; mi++)
#pragma unroll
                for (int ni = 0; ni < 4; ni++)
                    qa[mi][ni] = MFMA16(bfr[ni], a[mi], qa[mi][ni]);
        }

#pragma unroll
        for (int mi = 0; mi < 4; mi++) {
            int r = rowbase + mi * 16 + l15;
            if (r >= M) continue;
            int bb = r / NN, n = r - bb * NN;
            if (n >= QQ) continue;
#pragma unroll
            for (int ni = 0; ni < 4; ni++) {
                int col0 = colbase + ni * 16 + kg * 4;
                uint2 pk; pk.x = cvtpk(qa[mi][ni][0], qa[mi][ni][1]);
                pk.y = cvtpk(qa[mi][ni][2], qa[mi][ni][3]);
                int hb = (col0 >> 5) * BB + bb;
                *reinterpret_cast<uint2*>(Cq + ((size_t)hb * QQ + n) * DD + (col0 & 31)) = pk;
            }
        }
    }
}

// ---------------- flash attention: 3-stage pipeline (QK | exp2 | PV lagged) ----------------
__global__ __launch_bounds__(256)
void attn_k(const u16* __restrict__ qm, const u16* __restrict__ km,
            const u16* __restrict__ vm, u16* __restrict__ Opb,
            float* __restrict__ lp)
{
    __shared__ u16 klds[2][64 * 32];
    __shared__ u16 vt[2][32 * 64];
    __shared__ u16 plds[4][2][16 * 64];

    const int bx = blockIdx.x;
    const int split = bx >> 6;
    const int rem = bx & 63;
    const int h = rem >> 3, b = rem & 7;
    const int bh = b * HH + h;
    const int hb = h * BB + b;
    const int tid = threadIdx.x;
    const int w = tid >> 6, l = tid & 63;
    const int l15 = l & 15, kg = l >> 4;
    const int tstart = split * 64;
    const int nt = (NN - tstart + TSTR - 1) / TSTR;

    const f32x4 fz = {0.f, 0.f, 0.f, 0.f};
    const short os = (short)0x3F80;
    const short8 ones = {os, os, os, os, os, os, os, os};

    const u16* kbase = km + (size_t)hb * PADN * DD;
    const u16* vbase = vm + (size_t)hb * PADN * DD;
    const u16* qbase = qm + (size_t)hb * QQ * DD;
    const int vkp = (tid & 31) * 2;
    const int vdg = (tid >> 5) * 4;

    const int krow  = (w << 4) + (l >> 2);
    const int kslot = (l & 3) ^ ((krow >> 1) & 3);
    const u16* ksrc = kbase + krow * DD + kslot * 8;

    short8 qfr[5];
#pragma unroll
    for (int qf = 0; qf < 5; qf++) {
        int qrow = w * 80 + qf * 16 + l15;
        int qc = qrow < QQ ? qrow : 0;
        qfr[qf] = *reinterpret_cast<const short8*>(qbase + (size_t)qc * DD + kg * 8);
    }

    f32x4 o[2][5]; float lpart[5];
#pragma unroll
    for (int qf = 0; qf < 5; qf++) { o[0][qf] = fz; o[1][qf] = fz; lpart[qf] = 0.f; }

    gload16(ksrc + (size_t)tstart * DD, (u16*)((char*)klds[0] + (w << 10)));
    ushort4 v0r = *reinterpret_cast<const ushort4*>(vbase + (size_t)(tstart + vkp) * DD + vdg);
    ushort4 v1r = *reinterpret_cast<const ushort4*>(vbase + (size_t)(tstart + vkp + 1) * DD + vdg);

    char* pl = (char*)plds[w];
    const int rdswz = ((l15 << 7) ^ ((l15 & 7) << 4)) + (kg << 4);
    const int wrbase = (l15 << 7) ^ ((l15 & 7) << 4);

    for (int t = 0; t < nt; ++t) {
        const int n0 = tstart + t * TSTR;
        char* vtb = (char*)vt[t & 1];
#pragma unroll
        for (int i = 0; i < 4; i++) {
            int row = vdg + i;
            unsigned int pk2 = (unsigned int)v0r[i] | ((unsigned int)v1r[i] << 16);
            int byteo = ((row << 7) + (vkp << 1)) ^ ((row & 7) << 4);
            *reinterpret_cast<unsigned int*>(vtb + byteo) = pk2;
        }
        __syncthreads();

        gload16(ksrc + (size_t)(n0 + TSTR) * DD, (u16*)((char*)klds[(t + 1) & 1] + (w << 10)));
        ushort4 v0n = *reinterpret_cast<const ushort4*>(vbase + (size_t)(n0 + TSTR + vkp) * DD + vdg);
        ushort4 v1n = *reinterpret_cast<const ushort4*>(vbase + (size_t)(n0 + TSTR + vkp + 1) * DD + vdg);

        short8 kf[4];
        { const char* klb = (const char*)klds[t & 1];
#pragma unroll
          for (int kb = 0; kb < 4; kb++) {
              int row = kb * 16 + l15;
              int off = (row << 6) + ((kg ^ ((row >> 1) & 3)) << 4);
              kf[kb] = *reinterpret_cast<const short8*>(klb + off);
          } }

        short8 va[2][2];
#pragma unroll
        for (int ks = 0; ks < 2; ks++)
#pragma unroll
            for (int dg = 0; dg < 2; dg++) {
                int row = dg * 16 + l15;
                int byteo = ((row << 7) + 64 * ks + 16 * kg) ^ ((row & 7) << 4);
                va[ks][dg] = *reinterpret_cast<const short8*>(vtb + byteo);
            }

        const bool tail = (n0 + 64 > NN);

        f32x4 sp[4];
#pragma unroll
        for (int qf = 0; qf < 5; qf++) {
            short8 pb0, pb1;
            if (qf >= 2) {
                const char* plr = pl + (((qf - 2) & 1) << 11);
                pb0 = *reinterpret_cast<const short8*>(plr + rdswz);
                pb1 = *reinterpret_cast<const short8*>(plr + rdswz + 64);
            }
            f32x4 sc[4];
            __builtin_amdgcn_s_setprio(1);
#pragma unroll
            for (int kb = 0; kb < 4; kb++)
                sc[kb] = MFMA16(kf[kb], qfr[qf], fz);
            __builtin_amdgcn_s_setprio(0);
            if (qf >= 1) {
                char* plw = pl + (((qf - 1) & 1) << 11);
#pragma unroll
                for (int kb = 0; kb < 4; kb++) {
                    float p0 = exp2f(sp[kb][0]);
                    float p1 = exp2f(sp[kb][1]);
                    float p2 = exp2f(sp[kb][2]);
                    float p3 = exp2f(sp[kb][3]);
                    if (tail) {
                        int kbase2 = n0 + 16 * kb + 4 * kg;
                        if (kbase2 + 0 >= NN) p0 = 0.f;
                        if (kbase2 + 1 >= NN) p1 = 0.f;
                        if (kbase2 + 2 >= NN) p2 = 0.f;
                        if (kbase2 + 3 >= NN) p3 = 0.f;
                    }
                    uint2 pw; pw.x = cvtpk(p0, p1); pw.y = cvtpk(p2, p3);
                    *reinterpret_cast<uint2*>(plw + (wrbase + ((16 * kb + 4 * kg) << 1))) = pw;
                }
            }
            if (qf >= 2) {
                __builtin_amdgcn_s_setprio(1);
                o[0][qf - 2] = MFMA16(va[0][0], pb0, o[0][qf - 2]);
                o[1][qf - 2] = MFMA16(va[0][1], pb0, o[1][qf - 2]);
                o[0][qf - 2] = MFMA16(va[1][0], pb1, o[0][qf - 2]);
                o[1][qf - 2] = MFMA16(va[1][1], pb1, o[1][qf - 2]);
                f32x4 tsum = MFMA16(ones, pb0, fz);
                tsum = MFMA16(ones, pb1, tsum);
                __builtin_amdgcn_s_setprio(0);
                lpart[qf - 2] += tsum[0];
            }
#pragma unroll
            for (int kb = 0; kb < 4; kb++) sp[kb] = sc[kb];
        }
        {
            const char* plr = pl + (1 << 11);
            short8 pb0 = *reinterpret_cast<const short8*>(plr + rdswz);
            short8 pb1 = *reinterpret_cast<const short8*>(plr + rdswz + 64);
            char* plw = pl + 0;
#pragma unroll
            for (int kb = 0; kb < 4; kb++) {
                float p0 = exp2f(sp[kb][0]);
                float p1 = exp2f(sp[kb][1]);
                float p2 = exp2f(sp[kb][2]);
                float p3 = exp2f(sp[kb][3]);
                if (tail) {
                    int kbase2 = n0 + 16 * kb + 4 * kg;
                    if (kbase2 + 0 >= NN) p0 = 0.f;
                    if (kbase2 + 1 >= NN) p1 = 0.f;
                    if (kbase2 + 2 >= NN) p2 = 0.f;
                    if (kbase2 + 3 >= NN) p3 = 0.f;
                }
                uint2 pw; pw.x = cvtpk(p0, p1); pw.y = cvtpk(p2, p3);
                *reinterpret_cast<uint2*>(plw + (wrbase + ((16 * kb + 4 * kg) << 1))) = pw;
            }
            __builtin_amdgcn_s_setprio(1);
            o[0][3] = MFMA16(va[0][0], pb0, o[0][3]);
            o[1][3] = MFMA16(va[0][1], pb0, o[1][3]);
            o[0][3] = MFMA16(va[1][0], pb1, o[0][3]);
            o[1][3] = MFMA16(va[1][1], pb1, o[1][3]);
            f32x4 tsum = MFMA16(ones, pb0, fz);
            tsum = MFMA16(ones, pb1, tsum);
            __builtin_amdgcn_s_setprio(0);
            lpart[3] += tsum[0];
        }
        {
            const char* plr = pl + 0;
            short8 pb0 = *reinterpret_cast<const short8*>(plr + rdswz);
            short8 pb1 = *reinterpret_cast<const short8*>(plr + rdswz + 64);
            __builtin_amdgcn_s_setprio(1);
            o[0][4] = MFMA16(va[0][0], pb0, o[0][4]);
            o[1][4] = MFMA16(va[0][1], pb0, o[1][4]);
            o[0][4] = MFMA16(va[1][0], pb1, o[0][4]);
            o[1][4] = MFMA16(va[1][1], pb1, o[1][4]);
            f32x4 tsum = MFMA16(ones, pb0, fz);
            tsum = MFMA16(ones, pb1, tsum);
            __builtin_amdgcn_s_setprio(0);
            lpart[4] += tsum[0];
        }
        v0r = v0n; v1r = v1n;
    }

    size_t pb = (size_t)(split * 64 + bh) * QQ;
#pragma unroll
    for (int qf = 0; qf < 5; qf++) {
        int q = w * 80 + qf * 16 + l15;
        if (q >= QQ) continue;
        size_t pr = pb + q;
        if (kg == 0) lp[pr] = lpart[qf];
        uint2 w0; w0.x = cvtpk(o[0][qf][0], o[0][qf][1]); w0.y = cvtpk(o[0][qf][2], o[0][qf][3]);
        uint2 w1; w1.x = cvtpk(o[1][qf][0], o[1][qf][1]); w1.y = cvtpk(o[1][qf][2], o[1][qf][3]);
        *reinterpret_cast<uint2*>(Opb + pr * DD + kg * 4)      = w0;
        *reinterpret_cast<uint2*>(Opb + pr * DD + 16 + kg * 4) = w1;
    }
}

// ---------------- fused: combine + proj GEMM + residual + LN2 ----------------
__global__ __launch_bounds__(256)
void cpl_k(const u16* __restrict__ Opb, const float* __restrict__ lp,
           const u16* __restrict__ WpT, const float* __restrict__ x,
           const float* __restrict__ g1, const float* __restrict__ w2,
           const float* __restrict__ b2, float* __restrict__ xqf, u16* __restrict__ xqb)
{
    __shared__ u16 albs[16 * 256];
    __shared__ float pdl[16][260];

    const int tid = threadIdx.x;
    const int r0 = blockIdx.x * 16;

    {
        int row = tid >> 4, cg = tid & 15;
        int r = r0 + row;
        int b = r / QQ, q = r - b * QQ;
        int h = cg >> 1;
        int dbase = (cg & 1) * 16;
        float acc[16];
#pragma unroll
        for (int j = 0; j < 16; j++) acc[j] = 0.f;
        float L = 0.f;
        for (int s = 0; s < NSPLIT; s++) {
            size_t pr = ((size_t)(s * 64) + b * 8 + h) * QQ + q;
            L += lp[pr];
            short8 v0 = *reinterpret_cast<const short8*>(Opb + pr * DD + dbase);
            short8 v1 = *reinterpret_cast<const short8*>(Opb + pr * DD + dbase + 8);
#pragma unroll
            for (int j = 0; j < 8; j++) {
                acc[j]     += b2f((u16)v0[j]);
                acc[8 + j] += b2f((u16)v1[j]);
            }
        }
        float inv = 1.0f / L;
        short8 o0, o1;
#pragma unroll
        for (int j = 0; j < 4; j++) {
            unsigned int a = cvtpk(acc[2 * j] * inv, acc[2 * j + 1] * inv);
            unsigned int bq = cvtpk(acc[8 + 2 * j] * inv, acc[9 + 2 * j] * inv);
            o0[2 * j] = (short)(a & 0xffff); o0[2 * j + 1] = (short)(a >> 16);
            o1[2 * j] = (short)(bq & 0xffff); o1[2 * j + 1] = (short)(bq >> 16);
        }
        char* lb = (char*)albs;
        int byte0 = (row << 9) + (cg << 5);
        *reinterpret_cast<short8*>(lb + ((byte0)      ^ ((row & 7) << 4))) = o0;
        *reinterpret_cast<short8*>(lb + ((byte0 + 16) ^ ((row & 7) << 4))) = o1;
    }
    __syncthreads();

    const int w = tid >> 6, l = tid & 63;
    const int l15 = l & 15, kg = l >> 4;
    {
        const f32x4 fz = {0.f, 0.f, 0.f, 0.f};
        const int colbase = w * 64;
        const u16* bp[4];
#pragma unroll
        for (int ni = 0; ni < 4; ni++)
            bp[ni] = WpT + (size_t)(colbase + ni * 16 + l15) * CC + kg * 8;
        f32x4 acc[4];
#pragma unroll
        for (int ni = 0; ni < 4; ni++) acc[ni] = fz;
        const char* lb = (const char*)albs;
        const int arow = l15 << 9;
        const int sw = (l15 & 7) << 4;
#pragma unroll
        for (int ks = 0; ks < 8; ks++) {
            short8 a = *reinterpret_cast<const short8*>(lb + (arow + ((kg * 16 + ks * 64) ^ sw)));
#pragma unroll
            for (int ni = 0; ni < 4; ni++) {
                short8 bfr = *reinterpret_cast<const short8*>(bp[ni] + ks * 32);
                acc[ni] = MFMA16(bfr, a, acc[ni]);
            }
        }
#pragma unroll
        for (int ni = 0; ni < 4; ni++) {
            float4 v; v.x = acc[ni][0]; v.y = acc[ni][1]; v.z = acc[ni][2]; v.w = acc[ni][3];
            *reinterpret_cast<float4*>(&pdl[l15][colbase + ni * 16 + kg * 4]) = v;
        }
    }
    __syncthreads();

    {
        int row = tid >> 4, cg = tid & 15;
        int r = r0 + row;
        int b = r / QQ, q = r - b * QQ;
        size_t xoff = ((size_t)b * NN + q) * CC + cg * 16;
        float val[16];
        float s = 0.f, s2 = 0.f;
#pragma unroll
        for (int j4 = 0; j4 < 4; j4++) {
            float4 xv = *reinterpret_cast<const float4*>(x + xoff + j4 * 4);
            float4 gv = *reinterpret_cast<const float4*>(g1 + cg * 16 + j4 * 4);
            int c = cg * 16 + j4 * 4;
            val[j4 * 4 + 0] = xv.x + gv.x * pdl[row][c + 0];
            val[j4 * 4 + 1] = xv.y + gv.y * pdl[row][c + 1];
            val[j4 * 4 + 2] = xv.z + gv.z * pdl[row][c + 2];
            val[j4 * 4 + 3] = xv.w + gv.w * pdl[row][c + 3];
#pragma unroll
            for (int j = 0; j < 4; j++) {
                float v = val[j4 * 4 + j];
                s += v; s2 += v * v;
            }
        }
#pragma unroll
        for (int m = 1; m < 16; m <<= 1) {
            s  += __shfl_xor(s,  m, 64);
            s2 += __shfl_xor(s2, m, 64);
        }
        float mean = s * (1.0f / CC);
        float rs = rsqrtf(s2 * (1.0f / CC) - mean * mean + 1e-5f);
        size_t roff = (size_t)r * CC + cg * 16;
#pragma unroll
        for (int j4 = 0; j4 < 4; j4++) {
            int c = cg * 16 + j4 * 4;
            float4 wv = *reinterpret_cast<const float4*>(w2 + c);
            float4 bb = *reinterpret_cast<const float4*>(b2 + c);
            float n0 = (val[j4 * 4 + 0] - mean) * rs * wv.x + bb.x;
            float n1 = (val[j4 * 4 + 1] - mean) * rs * wv.y + bb.y;
            float n2 = (val[j4 * 4 + 2] - mean) * rs * wv.z + bb.z;
            float n3 = (val[j4 * 4 + 3] - mean) * rs * wv.w + bb.w;
            float4 o; o.x = n0; o.y = n1; o.z = n2; o.w = n3;
            *reinterpret_cast<float4*>(xqf + roff + j4 * 4) = o;
            uint2 u; u.x = cvtpk(n0, n1); u.y = cvtpk(n2, n3);
            *reinterpret_cast<uint2*>(xqb + roff + j4 * 4) = u;
        }
    }
}

// ---------------- fused MLP ----------------
__global__ __launch_bounds__(256)
void mlp_k(const u16* __restrict__ xqb, const u16* __restrict__ W1T,
           const u16* __restrict__ W2T, const float* __restrict__ xqf,
           const float* __restrict__ g2, float* __restrict__ out)
{
    __shared__ u16 h1l[16 * 1024];

    const int tid = threadIdx.x;
    const int w = tid >> 6, l = tid & 63;
    const int l15 = l & 15, kg = l >> 4;
    const int r0 = blockIdx.x * 16;
    const f32x4 fz = {0.f, 0.f, 0.f, 0.f};

    {
        const u16* ap = xqb + (size_t)(r0 + l15) * CC + kg * 8;
        f32x4 acc[16];
#pragma unroll
        for (int ni = 0; ni < 16; ni++) acc[ni] = fz;
#pragma unroll
        for (int ks = 0; ks < 8; ks++) {
            short8 a = *reinterpret_cast<const short8*>(ap + ks * 32);
#pragma unroll
            for (int ni = 0; ni < 16; ni++) {
                const u16* bp = W1T + (size_t)(w * 256 + ni * 16 + l15) * CC + kg * 8 + ks * 32;
                short8 bfr = *reinterpret_cast<const short8*>(bp);
                acc[ni] = MFMA16(bfr, a, acc[ni]);
            }
        }
        char* lb = (char*)h1l;
        const int sw = (l15 & 7) << 4;
#pragma unroll
        for (int ni = 0; ni < 16; ni++) {
            float g0 = 0.5f * acc[ni][0] * (1.0f + erff(acc[ni][0] * 0.70710678118654752f));
            float g1v = 0.5f * acc[ni][1] * (1.0f + erff(acc[ni][1] * 0.70710678118654752f));
            float g2v = 0.5f * acc[ni][2] * (1.0f + erff(acc[ni][2] * 0.70710678118654752f));
            float g3 = 0.5f * acc[ni][3] * (1.0f + erff(acc[ni][3] * 0.70710678118654752f));
            uint2 pk; pk.x = cvtpk(g0, g1v); pk.y = cvtpk(g2v, g3);
            int byteo = (l15 << 11) + (((w * 256 + ni * 16 + kg * 4) << 1) ^ sw);
            *reinterpret_cast<uint2*>(lb + byteo) = pk;
        }
    }
    __syncthreads();

    {
        const int colbase = w * 64;
        const u16* bp[4];
#pragma unroll
        for (int ni = 0; ni < 4; ni++)
            bp[ni] = W2T + (size_t)(colbase + ni * 16 + l15) * HIDN + kg * 8;
        f32x4 acc[4];
#pragma unroll
        for (int ni = 0; ni < 4; ni++) acc[ni] = fz;
        const char* lb = (const char*)h1l;
        const int arow = l15 << 11;
        const int sw = (l15 & 7) << 4;
#pragma unroll
        for (int ks = 0; ks < 32; ks++) {
            short8 a = *reinterpret_cast<const short8*>(lb + arow + (((kg * 8 + ks * 32) << 1) ^ sw));
#pragma unroll
            for (int ni = 0; ni < 4; ni++) {
                short8 bfr = *reinterpret_cast<const short8*>(bp[ni] + ks * 32);
                acc[ni] = MFMA16(bfr, a, acc[ni]);
            }
        }
        int r = r0 + l15;
        size_t orow = (size_t)(r / QQ) * NN + (r % QQ);
#pragma unroll
        for (int ni = 0; ni < 4; ni++) {
            int col0 = colbase + ni * 16 + kg * 4;
            float4 xv = *reinterpret_cast<const float4*>(xqf + (size_t)r * CC + col0);
            float4 gv = *reinterpret_cast<const float4*>(g2 + col0);
            float4 o;
            o.x = xv.x + gv.x * acc[ni][0];
            o.y = xv.y + gv.y * acc[ni][1];
            o.z = xv.z + gv.z * acc[ni][2];
            o.w = xv.w + gv.w * acc[ni][3];
            *reinterpret_cast<float4*>(out + orow * CC + col0) = o;
        }
    }
}

// ---------------- launch ----------------
extern "C" void kernel_launch(void* const* d_in, const int* in_sizes, int n_in,
                              void* d_out, int out_size, void* d_ws, size_t ws_size,
                              hipStream_t stream)
{
    (void)in_sizes; (void)n_in; (void)out_size; (void)ws_size;
    const float* x    = (const float*)d_in[0];
    const float* Wq   = (const float*)d_in[1];
    const float* Wk   = (const float*)d_in[2];
    const float* Wv   = (const float*)d_in[3];
    const float* Wp   = (const float*)d_in[4];
    const float* W1   = (const float*)d_in[5];
    const float* W2   = (const float*)d_in[6];
    const float* ln1w = (const float*)d_in[7];
    const float* ln1b = (const float*)d_in[8];
    const float* ln2w = (const float*)d_in[9];
    const float* ln2b = (const float*)d_in[10];
    const float* g1   = (const float*)d_in[11];
    const float* g2   = (const float*)d_in[12];
    float* out = (float*)d_out;

    char* p = (char*)d_ws;
    auto alloc = [&](size_t bytes) { char* r = p; p += (bytes + 255) & ~(size_t)255; return r; };

    const size_t MKV = (size_t)BB * NN;        // 69600
    const size_t MQ  = (size_t)BB * QQ;        // 2400

    u16* WqT  = (u16*)alloc((size_t)CC * CC * 2);
    u16* WkvT = (u16*)alloc((size_t)CC * CC * 2 * 2);
    u16* WpT  = (u16*)alloc((size_t)CC * CC * 2);
    u16* W1T  = (u16*)alloc((size_t)CC * HIDN * 2);
    u16* W2T  = (u16*)alloc((size_t)HIDN * CC * 2);
    u16* xn   = (u16*)alloc((MKV + 64) * CC * 2);
    u16* kbf  = (u16*)alloc((size_t)64 * PADN * DD * 2);   // head-major [h*8+b][n][32]
    u16* vbf  = (u16*)alloc((size_t)64 * PADN * DD * 2);
    u16* qbf  = (u16*)alloc((size_t)64 * QQ * DD * 2);
    u16* xqb  = (u16*)alloc(MQ * CC * 2);
    float* xqf = (float*)alloc(MQ * CC * 4);
    u16* Opb  = (u16*)alloc((size_t)NSPLIT * 64 * QQ * DD * 2);
    float* lp  = (float*)alloc((size_t)NSPLIT * 64 * QQ * 4);

    const float qscale = 0.17677669529663687f * 1.4426950408889634f;

    prep_k<<<17592, 256, 0, stream>>>(x, ln1w, ln1b, g1, xn, out,
                                      Wq, Wk, Wv, Wp, W1, W2, WqT, qscale);

    gemm_kv<<<1088, 512, 0, stream>>>(xn, WkvT, WqT, kbf, vbf, qbf, (int)MKV);

    attn_k<<<64 * NSPLIT, 256, 0, stream>>>(qbf, kbf, vbf, Opb, lp);

    cpl_k<<<150, 256, 0, stream>>>(Opb, lp, WpT, x, g1, ln2w, ln2b, xqf, xqb);

    mlp_k<<<150, 256, 0, stream>>>(xqb, W1T, W2T, xqf, g2, out);
}

// Round 17
// 217.960 us; speedup vs baseline: 1.0259x; 1.0259x over previous
//
#include <hip/hip_runtime.h>

#define BB 8
#define NN 8700
#define CC 256
#define QQ 300
#define HH 8
#define DD 32
#define HIDN 1024
#define NSPLIT 16
#define TSTR (NSPLIT * 64)
#define KSLACK 1536
#define PADN (NN + KSLACK)

typedef unsigned short u16;
typedef __attribute__((ext_vector_type(8))) short short8;
typedef __attribute__((ext_vector_type(4))) float f32x4;

#define MFMA16(a, b, c) __builtin_amdgcn_mfma_f32_16x16x32_bf16((a), (b), (c), 0, 0, 0)

__device__ __forceinline__ unsigned int cvtpk(float lo, float hi) {
    unsigned int r;
    asm("v_cvt_pk_bf16_f32 %0, %1, %2" : "=v"(r) : "v"(lo), "v"(hi));
    return r;
}
__device__ __forceinline__ u16 f2b_hw(float f) { return (u16)cvtpk(f, 0.f); }
__device__ __forceinline__ float b2f(u16 u) {
    unsigned int x = ((unsigned int)u) << 16;
    return __builtin_bit_cast(float, x);
}
__device__ __forceinline__ void gload16(const u16* g, u16* l) {
    __builtin_amdgcn_global_load_lds(
        (const __attribute__((address_space(1))) void*)g,
        (__attribute__((address_space(3))) void*)l, 16, 0, 0);
}

// ---------------- fused: LN1 (+context out) ∪ weight transpose ----------------
__global__ __launch_bounds__(256)
void prep_k(const float* __restrict__ x, const float* __restrict__ ln1w,
            const float* __restrict__ ln1b, const float* __restrict__ g1,
            u16* __restrict__ xn, float* __restrict__ out,
            const float* __restrict__ Wq, const float* __restrict__ Wk,
            const float* __restrict__ Wv, const float* __restrict__ Wp,
            const float* __restrict__ W1, const float* __restrict__ W2,
            u16* __restrict__ wdst, float qscale)
{
    __shared__ u16 tl[64][66];
    if (blockIdx.x < 17400) {
        int row = blockIdx.x * 4 + (threadIdx.x >> 6);
        int l = threadIdx.x & 63;
        size_t base = (size_t)row * CC + l * 4;
        float4 xv = *reinterpret_cast<const float4*>(x + base);
        float s  = xv.x + xv.y + xv.z + xv.w;
        float s2 = xv.x * xv.x + xv.y * xv.y + xv.z * xv.z + xv.w * xv.w;
#pragma unroll
        for (int m = 1; m < 64; m <<= 1) {
            s  += __shfl_xor(s,  m, 64);
            s2 += __shfl_xor(s2, m, 64);
        }
        float mean = s * (1.0f / CC);
        float rs = rsqrtf(s2 * (1.0f / CC) - mean * mean + 1e-5f);
        float4 wv = *reinterpret_cast<const float4*>(ln1w + l * 4);
        float4 bb = *reinterpret_cast<const float4*>(ln1b + l * 4);
        float n0 = (xv.x - mean) * rs * wv.x + bb.x;
        float n1 = (xv.y - mean) * rs * wv.y + bb.y;
        float n2 = (xv.z - mean) * rs * wv.z + bb.z;
        float n3 = (xv.w - mean) * rs * wv.w + bb.w;
        uint2 u; u.x = cvtpk(n0, n1); u.y = cvtpk(n2, n3);
        *reinterpret_cast<uint2*>(xn + base) = u;
        int n = row % NN;
        if (n >= QQ) {
            float4 gv = *reinterpret_cast<const float4*>(g1 + l * 4);
            float4 o;
            o.x = 2.0f * (xv.x + gv.x * n0);
            o.y = 2.0f * (xv.y + gv.y * n1);
            o.z = 2.0f * (xv.z + gv.z * n2);
            o.w = 2.0f * (xv.w + gv.w * n3);
            *reinterpret_cast<float4*>(out + base) = o;
        }
    } else {
        int bid = blockIdx.x - 17400;
        const float* src; int K, N, tr, tc; size_t dof; float sc = 1.f;
        if (bid < 64) {
            int mat = bid >> 4, ti = bid & 15;
            src = (mat == 0) ? Wq : (mat == 1) ? Wk : (mat == 2) ? Wv : Wp;
            K = 256; N = 256; tr = ti >> 2; tc = ti & 3;
            dof = (size_t)mat * 65536;
            if (mat == 0) sc = qscale;
        } else if (bid < 128) {
            int ti = bid - 64; src = W1; K = 256; N = 1024; tr = ti >> 4; tc = ti & 15; dof = 262144;
        } else {
            int ti = bid - 128; src = W2; K = 1024; N = 256; tr = ti >> 2; tc = ti & 3; dof = 524288;
        }
        int tid = threadIdx.x;
        int jj = tid & 63;
        int i0 = tid >> 6;
#pragma unroll
        for (int ii = 0; ii < 16; ii++) {
            int kk = i0 * 16 + ii;
            float v = src[(size_t)(tr * 64 + kk) * N + tc * 64 + jj] * sc;
            tl[kk][jj] = f2b_hw(v);
        }
        __syncthreads();
#pragma unroll
        for (int ii = 0; ii < 16; ii++) {
            int nn = i0 * 16 + ii;
            wdst[dof + (size_t)(tc * 64 + nn) * K + tr * 64 + jj] = tl[jj][nn];
        }
    }
}

// ---------------- KV projection: head-major output [h*8+b][n][32] ----------------
__global__ __launch_bounds__(512)
void gemm_kv(const u16* __restrict__ A, const u16* __restrict__ WT,
             u16* __restrict__ Cb, u16* __restrict__ Cb2, int M)
{
    __shared__ u16 alds[64 * 256];   // 32 KiB
    const int tid = threadIdx.x;
    const int w = tid >> 6, l = tid & 63;
    const int l15 = l & 15, kg = l >> 4;
    const int rowbase = blockIdx.x * 64;
    const f32x4 fz = {0.f, 0.f, 0.f, 0.f};

    {
        const char* gb = (const char*)(A + (size_t)rowbase * CC);
        char* lb = (char*)alds;
#pragma unroll
        for (int j = 0; j < 4; j++) {
            int o = tid * 64 + j * 16;
            short8 v = *reinterpret_cast<const short8*>(gb + o);
            int d = o ^ (((o >> 9) & 7) << 4);
            *reinterpret_cast<short8*>(lb + d) = v;
        }
    }
    __syncthreads();

    const int colbase = w * 64;
    const u16* bp[4];
#pragma unroll
    for (int ni = 0; ni < 4; ni++)
        bp[ni] = WT + (size_t)(colbase + ni * 16 + l15) * CC + kg * 8;

    f32x4 acc[4][4];
#pragma unroll
    for (int mi = 0; mi < 4; mi++)
#pragma unroll
        for (int ni = 0; ni < 4; ni++) acc[mi][ni] = fz;

    const char* lb = (const char*)alds;
    const int sw = (l15 & 7) << 4;
    int abase[4];
#pragma unroll
    for (int mi = 0; mi < 4; mi++) abase[mi] = (mi * 16 + l15) << 9;

#pragma unroll
    for (int ks = 0; ks < 8; ks++) {
        const int koff = ((ks * 64) + (kg * 16)) ^ sw;
        short8 a[4], bfr[4];
#pragma unroll
        for (int mi = 0; mi < 4; mi++)
            a[mi] = *reinterpret_cast<const short8*>(lb + abase[mi] + koff);
#pragma unroll
        for (int ni = 0; ni < 4; ni++)
            bfr[ni] = *reinterpret_cast<const short8*>(bp[ni] + ks * 32);
#pragma unroll
        for (int mi = 0; mi < 4; mi++)
#pragma unroll
            for (int ni = 0; ni < 4; ni++)
                acc[mi][ni] = MFMA16(bfr[ni], a[mi], acc[mi][ni]);
    }

#pragma unroll
    for (int mi = 0; mi < 4; mi++) {
        int r = rowbase + mi * 16 + l15;
        if (r >= M) continue;
        int bb = r / NN, n = r - bb * NN;
#pragma unroll
        for (int ni = 0; ni < 4; ni++) {
            int col0 = colbase + ni * 16 + kg * 4;
            f32x4 v = acc[mi][ni];
            uint2 pk; pk.x = cvtpk(v[0], v[1]); pk.y = cvtpk(v[2], v[3]);
            int c = (col0 < CC) ? col0 : col0 - CC;
            int hb = (c >> 5) * BB + bb;
            size_t off = ((size_t)hb * PADN + n) * DD + (c & 31);
            if (col0 < CC) *reinterpret_cast<uint2*>(Cb  + off) = pk;
            else           *reinterpret_cast<uint2*>(Cb2 + off) = pk;
        }
    }
}

// ---------------- Q projection: head-major output [h*8+b][q][32] ----------------
__global__ __launch_bounds__(256)
void gemm_q(const u16* __restrict__ A, const u16* __restrict__ WT, u16* __restrict__ Cb, int M)
{
    const int w = threadIdx.x >> 6, l = threadIdx.x & 63;
    const int l15 = l & 15, kg = l >> 4;
    const int rowbase = blockIdx.x * 16;
    const int colbase = w * 64;
    const short8 z8 = {0, 0, 0, 0, 0, 0, 0, 0};
    const f32x4 fz = {0.f, 0.f, 0.f, 0.f};

    int r = rowbase + l15;
    bool av = (r < M);
    int rr = av ? r : 0;
    const u16* ap = A + ((size_t)(rr / QQ) * NN + (rr % QQ)) * CC + kg * 8;
    const u16* bp[4];
#pragma unroll
    for (int ni = 0; ni < 4; ni++)
        bp[ni] = WT + (size_t)(colbase + ni * 16 + l15) * CC + kg * 8;

    f32x4 acc[4];
#pragma unroll
    for (int ni = 0; ni < 4; ni++) acc[ni] = fz;

    for (int ks = 0; ks < CC; ks += 32) {
        short8 a = av ? *reinterpret_cast<const short8*>(ap + ks) : z8;
#pragma unroll
        for (int ni = 0; ni < 4; ni++) {
            short8 bfr = *reinterpret_cast<const short8*>(bp[ni] + ks);
            acc[ni] = MFMA16(bfr, a, acc[ni]);
        }
    }
    if (r < M) {
        int bb = r / QQ, q = r - bb * QQ;
#pragma unroll
        for (int ni = 0; ni < 4; ni++) {
            int col0 = colbase + ni * 16 + kg * 4;
            uint2 pk; pk.x = cvtpk(acc[ni][0], acc[ni][1]); pk.y = cvtpk(acc[ni][2], acc[ni][3]);
            int hb = (col0 >> 5) * BB + bb;
            *reinterpret_cast<uint2*>(Cb + ((size_t)hb * QQ + q) * DD + (col0 & 31)) = pk;
        }
    }
}

// ---------------- flash attention: 3-stage pipeline (QK | exp2 | PV lagged) ----------------
__global__ __launch_bounds__(256)
void attn_k(const u16* __restrict__ qm, const u16* __restrict__ km,
            const u16* __restrict__ vm, u16* __restrict__ Opb,
            float* __restrict__ lp)
{
    __shared__ u16 klds[2][64 * 32];
    __shared__ u16 vt[2][32 * 64];
    __shared__ u16 plds[4][2][16 * 64];

    const int bx = blockIdx.x;
    const int split = bx >> 6;
    const int rem = bx & 63;
    const int h = rem >> 3, b = rem & 7;
    const int bh = b * HH + h;
    const int hb = h * BB + b;
    const int tid = threadIdx.x;
    const int w = tid >> 6, l = tid & 63;
    const int l15 = l & 15, kg = l >> 4;
    const int tstart = split * 64;
    const int nt = (NN - tstart + TSTR - 1) / TSTR;

    const f32x4 fz = {0.f, 0.f, 0.f, 0.f};
    const short os = (short)0x3F80;
    const short8 ones = {os, os, os, os, os, os, os, os};

    const u16* kbase = km + (size_t)hb * PADN * DD;
    const u16* vbase = vm + (size_t)hb * PADN * DD;
    const u16* qbase = qm + (size_t)hb * QQ * DD;
    const int vkp = (tid & 31) * 2;
    const int vdg = (tid >> 5) * 4;

    const int krow  = (w << 4) + (l >> 2);
    const int kslot = (l & 3) ^ ((krow >> 1) & 3);
    const u16* ksrc = kbase + krow * DD + kslot * 8;

    short8 qfr[5];
#pragma unroll
    for (int qf = 0; qf < 5; qf++) {
        int qrow = w * 80 + qf * 16 + l15;
        int qc = qrow < QQ ? qrow : 0;
        qfr[qf] = *reinterpret_cast<const short8*>(qbase + (size_t)qc * DD + kg * 8);
    }

    f32x4 o[2][5]; float lpart[5];
#pragma unroll
    for (int qf = 0; qf < 5; qf++) { o[0][qf] = fz; o[1][qf] = fz; lpart[qf] = 0.f; }

    gload16(ksrc + (size_t)tstart * DD, (u16*)((char*)klds[0] + (w << 10)));
    ushort4 v0r = *reinterpret_cast<const ushort4*>(vbase + (size_t)(tstart + vkp) * DD + vdg);
    ushort4 v1r = *reinterpret_cast<const ushort4*>(vbase + (size_t)(tstart + vkp + 1) * DD + vdg);

    char* pl = (char*)plds[w];
    const int rdswz = ((l15 << 7) ^ ((l15 & 7) << 4)) + (kg << 4);
    const int wrbase = (l15 << 7) ^ ((l15 & 7) << 4);

    for (int t = 0; t < nt; ++t) {
        const int n0 = tstart + t * TSTR;
        char* vtb = (char*)vt[t & 1];
#pragma unroll
        for (int i = 0; i < 4; i++) {
            int row = vdg + i;
            unsigned int pk2 = (unsigned int)v0r[i] | ((unsigned int)v1r[i] << 16);
            int byteo = ((row << 7) + (vkp << 1)) ^ ((row & 7) << 4);
            *reinterpret_cast<unsigned int*>(vtb + byteo) = pk2;
        }
        __syncthreads();

        gload16(ksrc + (size_t)(n0 + TSTR) * DD, (u16*)((char*)klds[(t + 1) & 1] + (w << 10)));
        ushort4 v0n = *reinterpret_cast<const ushort4*>(vbase + (size_t)(n0 + TSTR + vkp) * DD + vdg);
        ushort4 v1n = *reinterpret_cast<const ushort4*>(vbase + (size_t)(n0 + TSTR + vkp + 1) * DD + vdg);

        short8 kf[4];
        { const char* klb = (const char*)klds[t & 1];
#pragma unroll
          for (int kb = 0; kb < 4; kb++) {
              int row = kb * 16 + l15;
              int off = (row << 6) + ((kg ^ ((row >> 1) & 3)) << 4);
              kf[kb] = *reinterpret_cast<const short8*>(klb + off);
          } }

        short8 va[2][2];
#pragma unroll
        for (int ks = 0; ks < 2; ks++)
#pragma unroll
            for (int dg = 0; dg < 2; dg++) {
                int row = dg * 16 + l15;
                int byteo = ((row << 7) + 64 * ks + 16 * kg) ^ ((row & 7) << 4);
                va[ks][dg] = *reinterpret_cast<const short8*>(vtb + byteo);
            }

        const bool tail = (n0 + 64 > NN);

        f32x4 sp[4];
#pragma unroll
        for (int qf = 0; qf < 5; qf++) {
            short8 pb0, pb1;
            if (qf >= 2) {
                const char* plr = pl + (((qf - 2) & 1) << 11);
                pb0 = *reinterpret_cast<const short8*>(plr + rdswz);
                pb1 = *reinterpret_cast<const short8*>(plr + rdswz + 64);
            }
            f32x4 sc[4];
            __builtin_amdgcn_s_setprio(1);
#pragma unroll
            for (int kb = 0; kb < 4; kb++)
                sc[kb] = MFMA16(kf[kb], qfr[qf], fz);
            __builtin_amdgcn_s_setprio(0);
            if (qf >= 1) {
                char* plw = pl + (((qf - 1) & 1) << 11);
#pragma unroll
                for (int kb = 0; kb < 4; kb++) {
                    float p0 = exp2f(sp[kb][0]);
                    float p1 = exp2f(sp[kb][1]);
                    float p2 = exp2f(sp[kb][2]);
                    float p3 = exp2f(sp[kb][3]);
                    if (tail) {
                        int kbase2 = n0 + 16 * kb + 4 * kg;
                        if (kbase2 + 0 >= NN) p0 = 0.f;
                        if (kbase2 + 1 >= NN) p1 = 0.f;
                        if (kbase2 + 2 >= NN) p2 = 0.f;
                        if (kbase2 + 3 >= NN) p3 = 0.f;
                    }
                    uint2 pw; pw.x = cvtpk(p0, p1); pw.y = cvtpk(p2, p3);
                    *reinterpret_cast<uint2*>(plw + (wrbase + ((16 * kb + 4 * kg) << 1))) = pw;
                }
            }
            if (qf >= 2) {
                __builtin_amdgcn_s_setprio(1);
                o[0][qf - 2] = MFMA16(va[0][0], pb0, o[0][qf - 2]);
                o[1][qf - 2] = MFMA16(va[0][1], pb0, o[1][qf - 2]);
                o[0][qf - 2] = MFMA16(va[1][0], pb1, o[0][qf - 2]);
                o[1][qf - 2] = MFMA16(va[1][1], pb1, o[1][qf - 2]);
                f32x4 tsum = MFMA16(ones, pb0, fz);
                tsum = MFMA16(ones, pb1, tsum);
                __builtin_amdgcn_s_setprio(0);
                lpart[qf - 2] += tsum[0];
            }
#pragma unroll
            for (int kb = 0; kb < 4; kb++) sp[kb] = sc[kb];
        }
        {
            const char* plr = pl + (1 << 11);
            short8 pb0 = *reinterpret_cast<const short8*>(plr + rdswz);
            short8 pb1 = *reinterpret_cast<const short8*>(plr + rdswz + 64);
            char* plw = pl + 0;
#pragma unroll
            for (int kb = 0; kb < 4; kb++) {
                float p0 = exp2f(sp[kb][0]);
                float p1 = exp2f(sp[kb][1]);
                float p2 = exp2f(sp[kb][2]);
                float p3 = exp2f(sp[kb][3]);
                if (tail) {
                    int kbase2 = n0 + 16 * kb + 4 * kg;
                    if (kbase2 + 0 >= NN) p0 = 0.f;
                    if (kbase2 + 1 >= NN) p1 = 0.f;
                    if (kbase2 + 2 >= NN) p2 = 0.f;
                    if (kbase2 + 3 >= NN) p3 = 0.f;
                }
                uint2 pw; pw.x = cvtpk(p0, p1); pw.y = cvtpk(p2, p3);
                *reinterpret_cast<uint2*>(plw + (wrbase + ((16 * kb + 4 * kg) << 1))) = pw;
            }
            __builtin_amdgcn_s_setprio(1);
            o[0][3] = MFMA16(va[0][0], pb0, o[0][3]);
            o[1][3] = MFMA16(va[0][1], pb0, o[1][3]);
            o[0][3] = MFMA16(va[1][0], pb1, o[0][3]);
            o[1][3] = MFMA16(va[1][1], pb1, o[1][3]);
            f32x4 tsum = MFMA16(ones, pb0, fz);
            tsum = MFMA16(ones, pb1, tsum);
            __builtin_amdgcn_s_setprio(0);
            lpart[3] += tsum[0];
        }
        {
            const char* plr = pl + 0;
            short8 pb0 = *reinterpret_cast<const short8*>(plr + rdswz);
            short8 pb1 = *reinterpret_cast<const short8*>(plr + rdswz + 64);
            __builtin_amdgcn_s_setprio(1);
            o[0][4] = MFMA16(va[0][0], pb0, o[0][4]);
            o[1][4] = MFMA16(va[0][1], pb0, o[1][4]);
            o[0][4] = MFMA16(va[1][0], pb1, o[0][4]);
            o[1][4] = MFMA16(va[1][1], pb1, o[1][4]);
            f32x4 tsum = MFMA16(ones, pb0, fz);
            tsum = MFMA16(ones, pb1, tsum);
            __builtin_amdgcn_s_setprio(0);
            lpart[4] += tsum[0];
        }
        v0r = v0n; v1r = v1n;
    }

    size_t pb = (size_t)(split * 64 + bh) * QQ;
#pragma unroll
    for (int qf = 0; qf < 5; qf++) {
        int q = w * 80 + qf * 16 + l15;
        if (q >= QQ) continue;
        size_t pr = pb + q;
        if (kg == 0) lp[pr] = lpart[qf];
        uint2 w0; w0.x = cvtpk(o[0][qf][0], o[0][qf][1]); w0.y = cvtpk(o[0][qf][2], o[0][qf][3]);
        uint2 w1; w1.x = cvtpk(o[1][qf][0], o[1][qf][1]); w1.y = cvtpk(o[1][qf][2], o[1][qf][3]);
        *reinterpret_cast<uint2*>(Opb + pr * DD + kg * 4)      = w0;
        *reinterpret_cast<uint2*>(Opb + pr * DD + 16 + kg * 4) = w1;
    }
}

// ---------------- fused: combine + proj GEMM + residual + LN2 ----------------
__global__ __launch_bounds__(256)
void cpl_k(const u16* __restrict__ Opb, const float* __restrict__ lp,
           const u16* __restrict__ WpT, const float* __restrict__ x,
           const float* __restrict__ g1, const float* __restrict__ w2,
           const float* __restrict__ b2, float* __restrict__ xqf, u16* __restrict__ xqb)
{
    __shared__ u16 albs[16 * 256];
    __shared__ float pdl[16][260];

    const int tid = threadIdx.x;
    const int r0 = blockIdx.x * 16;

    {
        int row = tid >> 4, cg = tid & 15;
        int r = r0 + row;
        int b = r / QQ, q = r - b * QQ;
        int h = cg >> 1;
        int dbase = (cg & 1) * 16;
        float acc[16];
#pragma unroll
        for (int j = 0; j < 16; j++) acc[j] = 0.f;
        float L = 0.f;
        for (int s = 0; s < NSPLIT; s++) {
            size_t pr = ((size_t)(s * 64) + b * 8 + h) * QQ + q;
            L += lp[pr];
            short8 v0 = *reinterpret_cast<const short8*>(Opb + pr * DD + dbase);
            short8 v1 = *reinterpret_cast<const short8*>(Opb + pr * DD + dbase + 8);
#pragma unroll
            for (int j = 0; j < 8; j++) {
                acc[j]     += b2f((u16)v0[j]);
                acc[8 + j] += b2f((u16)v1[j]);
            }
        }
        float inv = 1.0f / L;
        short8 o0, o1;
#pragma unroll
        for (int j = 0; j < 4; j++) {
            unsigned int a = cvtpk(acc[2 * j] * inv, acc[2 * j + 1] * inv);
            unsigned int bq = cvtpk(acc[8 + 2 * j] * inv, acc[9 + 2 * j] * inv);
            o0[2 * j] = (short)(a & 0xffff); o0[2 * j + 1] = (short)(a >> 16);
            o1[2 * j] = (short)(bq & 0xffff); o1[2 * j + 1] = (short)(bq >> 16);
        }
        char* lb = (char*)albs;
        int byte0 = (row << 9) + (cg << 5);
        *reinterpret_cast<short8*>(lb + ((byte0)      ^ ((row & 7) << 4))) = o0;
        *reinterpret_cast<short8*>(lb + ((byte0 + 16) ^ ((row & 7) << 4))) = o1;
    }
    __syncthreads();

    const int w = tid >> 6, l = tid & 63;
    const int l15 = l & 15, kg = l >> 4;
    {
        const f32x4 fz = {0.f, 0.f, 0.f, 0.f};
        const int colbase = w * 64;
        const u16* bp[4];
#pragma unroll
        for (int ni = 0; ni < 4; ni++)
            bp[ni] = WpT + (size_t)(colbase + ni * 16 + l15) * CC + kg * 8;
        f32x4 acc[4];
#pragma unroll
        for (int ni = 0; ni < 4; ni++) acc[ni] = fz;
        const char* lb = (const char*)albs;
        const int arow = l15 << 9;
        const int sw = (l15 & 7) << 4;
#pragma unroll
        for (int ks = 0; ks < 8; ks++) {
            short8 a = *reinterpret_cast<const short8*>(lb + (arow + ((kg * 16 + ks * 64) ^ sw)));
#pragma unroll
            for (int ni = 0; ni < 4; ni++) {
                short8 bfr = *reinterpret_cast<const short8*>(bp[ni] + ks * 32);
                acc[ni] = MFMA16(bfr, a, acc[ni]);
            }
        }
#pragma unroll
        for (int ni = 0; ni < 4; ni++) {
            float4 v; v.x = acc[ni][0]; v.y = acc[ni][1]; v.z = acc[ni][2]; v.w = acc[ni][3];
            *reinterpret_cast<float4*>(&pdl[l15][colbase + ni * 16 + kg * 4]) = v;
        }
    }
    __syncthreads();

    {
        int row = tid >> 4, cg = tid & 15;
        int r = r0 + row;
        int b = r / QQ, q = r - b * QQ;
        size_t xoff = ((size_t)b * NN + q) * CC + cg * 16;
        float val[16];
        float s = 0.f, s2 = 0.f;
#pragma unroll
        for (int j4 = 0; j4 < 4; j4++) {
            float4 xv = *reinterpret_cast<const float4*>(x + xoff + j4 * 4);
            float4 gv = *reinterpret_cast<const float4*>(g1 + cg * 16 + j4 * 4);
            int c = cg * 16 + j4 * 4;
            val[j4 * 4 + 0] = xv.x + gv.x * pdl[row][c + 0];
            val[j4 * 4 + 1] = xv.y + gv.y * pdl[row][c + 1];
            val[j4 * 4 + 2] = xv.z + gv.z * pdl[row][c + 2];
            val[j4 * 4 + 3] = xv.w + gv.w * pdl[row][c + 3];
#pragma unroll
            for (int j = 0; j < 4; j++) {
                float v = val[j4 * 4 + j];
                s += v; s2 += v * v;
            }
        }
#pragma unroll
        for (int m = 1; m < 16; m <<= 1) {
            s  += __shfl_xor(s,  m, 64);
            s2 += __shfl_xor(s2, m, 64);
        }
        float mean = s * (1.0f / CC);
        float rs = rsqrtf(s2 * (1.0f / CC) - mean * mean + 1e-5f);
        size_t roff = (size_t)r * CC + cg * 16;
#pragma unroll
        for (int j4 = 0; j4 < 4; j4++) {
            int c = cg * 16 + j4 * 4;
            float4 wv = *reinterpret_cast<const float4*>(w2 + c);
            float4 bb = *reinterpret_cast<const float4*>(b2 + c);
            float n0 = (val[j4 * 4 + 0] - mean) * rs * wv.x + bb.x;
            float n1 = (val[j4 * 4 + 1] - mean) * rs * wv.y + bb.y;
            float n2 = (val[j4 * 4 + 2] - mean) * rs * wv.z + bb.z;
            float n3 = (val[j4 * 4 + 3] - mean) * rs * wv.w + bb.w;
            float4 o; o.x = n0; o.y = n1; o.z = n2; o.w = n3;
            *reinterpret_cast<float4*>(xqf + roff + j4 * 4) = o;
            uint2 u; u.x = cvtpk(n0, n1); u.y = cvtpk(n2, n3);
            *reinterpret_cast<uint2*>(xqb + roff + j4 * 4) = u;
        }
    }
}

// ---------------- fused MLP ----------------
__global__ __launch_bounds__(256)
void mlp_k(const u16* __restrict__ xqb, const u16* __restrict__ W1T,
           const u16* __restrict__ W2T, const float* __restrict__ xqf,
           const float* __restrict__ g2, float* __restrict__ out)
{
    __shared__ u16 h1l[16 * 1024];

    const int tid = threadIdx.x;
    const int w = tid >> 6, l = tid & 63;
    const int l15 = l & 15, kg = l >> 4;
    const int r0 = blockIdx.x * 16;
    const f32x4 fz = {0.f, 0.f, 0.f, 0.f};

    {
        const u16* ap = xqb + (size_t)(r0 + l15) * CC + kg * 8;
        f32x4 acc[16];
#pragma unroll
        for (int ni = 0; ni < 16; ni++) acc[ni] = fz;
#pragma unroll
        for (int ks = 0; ks < 8; ks++) {
            short8 a = *reinterpret_cast<const short8*>(ap + ks * 32);
#pragma unroll
            for (int ni = 0; ni < 16; ni++) {
                const u16* bp = W1T + (size_t)(w * 256 + ni * 16 + l15) * CC + kg * 8 + ks * 32;
                short8 bfr = *reinterpret_cast<const short8*>(bp);
                acc[ni] = MFMA16(bfr, a, acc[ni]);
            }
        }
        char* lb = (char*)h1l;
        const int sw = (l15 & 7) << 4;
#pragma unroll
        for (int ni = 0; ni < 16; ni++) {
            float g0 = 0.5f * acc[ni][0] * (1.0f + erff(acc[ni][0] * 0.70710678118654752f));
            float g1v = 0.5f * acc[ni][1] * (1.0f + erff(acc[ni][1] * 0.70710678118654752f));
            float g2v = 0.5f * acc[ni][2] * (1.0f + erff(acc[ni][2] * 0.70710678118654752f));
            float g3 = 0.5f * acc[ni][3] * (1.0f + erff(acc[ni][3] * 0.70710678118654752f));
            uint2 pk; pk.x = cvtpk(g0, g1v); pk.y = cvtpk(g2v, g3);
            int byteo = (l15 << 11) + (((w * 256 + ni * 16 + kg * 4) << 1) ^ sw);
            *reinterpret_cast<uint2*>(lb + byteo) = pk;
        }
    }
    __syncthreads();

    {
        const int colbase = w * 64;
        const u16* bp[4];
#pragma unroll
        for (int ni = 0; ni < 4; ni++)
            bp[ni] = W2T + (size_t)(colbase + ni * 16 + l15) * HIDN + kg * 8;
        f32x4 acc[4];
#pragma unroll
        for (int ni = 0; ni < 4; ni++) acc[ni] = fz;
        const char* lb = (const char*)h1l;
        const int arow = l15 << 11;
        const int sw = (l15 & 7) << 4;
#pragma unroll
        for (int ks = 0; ks < 32; ks++) {
            short8 a = *reinterpret_cast<const short8*>(lb + arow + (((kg * 8 + ks * 32) << 1) ^ sw));
#pragma unroll
            for (int ni = 0; ni < 4; ni++) {
                short8 bfr = *reinterpret_cast<const short8*>(bp[ni] + ks * 32);
                acc[ni] = MFMA16(bfr, a, acc[ni]);
            }
        }
        int r = r0 + l15;
        size_t orow = (size_t)(r / QQ) * NN + (r % QQ);
#pragma unroll
        for (int ni = 0; ni < 4; ni++) {
            int col0 = colbase + ni * 16 + kg * 4;
            float4 xv = *reinterpret_cast<const float4*>(xqf + (size_t)r * CC + col0);
            float4 gv = *reinterpret_cast<const float4*>(g2 + col0);
            float4 o;
            o.x = xv.x + gv.x * acc[ni][0];
            o.y = xv.y + gv.y * acc[ni][1];
            o.z = xv.z + gv.z * acc[ni][2];
            o.w = xv.w + gv.w * acc[ni][3];
            *reinterpret_cast<float4*>(out + orow * CC + col0) = o;
        }
    }
}

// ---------------- launch ----------------
extern "C" void kernel_launch(void* const* d_in, const int* in_sizes, int n_in,
                              void* d_out, int out_size, void* d_ws, size_t ws_size,
                              hipStream_t stream)
{
    (void)in_sizes; (void)n_in; (void)out_size; (void)ws_size;
    const float* x    = (const float*)d_in[0];
    const float* Wq   = (const float*)d_in[1];
    const float* Wk   = (const float*)d_in[2];
    const float* Wv   = (const float*)d_in[3];
    const float* Wp   = (const float*)d_in[4];
    const float* W1   = (const float*)d_in[5];
    const float* W2   = (const float*)d_in[6];
    const float* ln1w = (const float*)d_in[7];
    const float* ln1b = (const float*)d_in[8];
    const float* ln2w = (const float*)d_in[9];
    const float* ln2b = (const float*)d_in[10];
    const float* g1   = (const float*)d_in[11];
    const float* g2   = (const float*)d_in[12];
    float* out = (float*)d_out;

    char* p = (char*)d_ws;
    auto alloc = [&](size_t bytes) { char* r = p; p += (bytes + 255) & ~(size_t)255; return r; };

    const size_t MKV = (size_t)BB * NN;        // 69600
    const size_t MQ  = (size_t)BB * QQ;        // 2400

    u16* WqT  = (u16*)alloc((size_t)CC * CC * 2);
    u16* WkvT = (u16*)alloc((size_t)CC * CC * 2 * 2);
    u16* WpT  = (u16*)alloc((size_t)CC * CC * 2);
    u16* W1T  = (u16*)alloc((size_t)CC * HIDN * 2);
    u16* W2T  = (u16*)alloc((size_t)HIDN * CC * 2);
    u16* xn   = (u16*)alloc((MKV + 64) * CC * 2);
    u16* kbf  = (u16*)alloc((size_t)64 * PADN * DD * 2);   // head-major [h*8+b][n][32]
    u16* vbf  = (u16*)alloc((size_t)64 * PADN * DD * 2);
    u16* qbf  = (u16*)alloc((size_t)64 * QQ * DD * 2);
    u16* xqb  = (u16*)alloc(MQ * CC * 2);
    float* xqf = (float*)alloc(MQ * CC * 4);
    u16* Opb  = (u16*)alloc((size_t)NSPLIT * 64 * QQ * DD * 2);
    float* lp  = (float*)alloc((size_t)NSPLIT * 64 * QQ * 4);

    const float qscale = 0.17677669529663687f * 1.4426950408889634f;

    prep_k<<<17592, 256, 0, stream>>>(x, ln1w, ln1b, g1, xn, out,
                                      Wq, Wk, Wv, Wp, W1, W2, WqT, qscale);

    gemm_kv<<<1088, 512, 0, stream>>>(xn, WkvT, kbf, vbf, (int)MKV);
    gemm_q<<<150, 256, 0, stream>>>(xn, WqT, qbf, (int)MQ);

    attn_k<<<64 * NSPLIT, 256, 0, stream>>>(qbf, kbf, vbf, Opb, lp);

    cpl_k<<<150, 256, 0, stream>>>(Opb, lp, WpT, x, g1, ln2w, ln2b, xqf, xqb);

    mlp_k<<<150, 256, 0, stream>>>(xqb, W1T, W2T, xqf, g2, out);
}